// Round 1
// baseline (553.314 us; speedup 1.0000x reference)
//
#include <hip/hip_runtime.h>

#define BB 4
#define CC 64
#define HH 256
#define WW 256
#define KK 9
#define NOFF 18
#define HO 254
#define WO 254

__global__ __launch_bounds__(256) void deform_fused_kernel(
    const float* __restrict__ x,
    const float* __restrict__ offset_w,
    const float* __restrict__ offset_b,
    const float* __restrict__ deform_w,
    const float* __restrict__ deform_b,
    float* __restrict__ out)
{
    // LDS-staged weights: offset_w [o][c][tap] 18*64*9, deform_w [c][tap] 64*9
    __shared__ float s_ow[NOFF * CC * KK];
    __shared__ float s_dw[CC * KK];
    __shared__ float s_ob[NOFF];

    for (int i = threadIdx.x; i < NOFF * CC * KK; i += blockDim.x) s_ow[i] = offset_w[i];
    for (int i = threadIdx.x; i < CC * KK; i += blockDim.x)        s_dw[i] = deform_w[i];
    if (threadIdx.x < NOFF) s_ob[threadIdx.x] = offset_b[threadIdx.x];
    __syncthreads();

    const int npix = BB * HO * WO;
    int pix = blockIdx.x * blockDim.x + threadIdx.x;
    if (pix >= npix) return;

    int b   = pix / (HO * WO);
    int rem = pix - b * (HO * WO);
    int ho  = rem / WO;
    int wo  = rem - ho * WO;

    const float* xb = x + (size_t)b * CC * HH * WW;

    // ---------- step 1: offset conv (valid 3x3, 18 out channels) ----------
    float accO[NOFF];
    #pragma unroll
    for (int o = 0; o < NOFF; ++o) accO[o] = s_ob[o];

    for (int c = 0; c < CC; ++c) {
        const float* xp = xb + c * (HH * WW) + ho * WW + wo;
        float xv[9];
        #pragma unroll
        for (int kh = 0; kh < 3; ++kh)
            #pragma unroll
            for (int kw = 0; kw < 3; ++kw)
                xv[kh * 3 + kw] = xp[kh * WW + kw];

        const float* wp = s_ow + c * KK;   // s_ow[o*CC*KK + c*KK + t]
        #pragma unroll
        for (int o = 0; o < NOFF; ++o) {
            const float* wop = wp + o * (CC * KK);
            #pragma unroll
            for (int t = 0; t < 9; ++t)
                accO[o] = fmaf(xv[t], wop[t], accO[o]);
        }
    }

    // ---------- step 2: deformable bilinear gather + dot ----------
    float acc = deform_b[0];

    #pragma unroll
    for (int k = 0; k < KK; ++k) {
        const int kh = k / 3;
        const int kw = k % 3;
        float dy = accO[2 * k];
        float dx = accO[2 * k + 1];
        float py = (float)(ho + kh) + dy;
        float px = (float)(wo + kw) + dx;

        float y0f = floorf(py);
        float x0f = floorf(px);
        float ly = py - y0f;
        float lx = px - x0f;
        int y0 = (int)y0f, x0 = (int)x0f;
        int y1 = y0 + 1,  x1 = x0 + 1;

        // bilinear weights, zeroed when the (unclipped) corner is out of bounds
        float w00 = (1.0f - ly) * (1.0f - lx);
        float w01 = (1.0f - ly) * lx;
        float w10 = ly * (1.0f - lx);
        float w11 = ly * lx;
        if (!(y0 >= 0 && y0 < HH && x0 >= 0 && x0 < WW)) w00 = 0.0f;
        if (!(y0 >= 0 && y0 < HH && x1 >= 0 && x1 < WW)) w01 = 0.0f;
        if (!(y1 >= 0 && y1 < HH && x0 >= 0 && x0 < WW)) w10 = 0.0f;
        if (!(y1 >= 0 && y1 < HH && x1 >= 0 && x1 < WW)) w11 = 0.0f;

        int y0c = min(max(y0, 0), HH - 1);
        int y1c = min(max(y1, 0), HH - 1);
        int x0c = min(max(x0, 0), WW - 1);
        int x1c = min(max(x1, 0), WW - 1);
        int i00 = y0c * WW + x0c;
        int i01 = y0c * WW + x1c;
        int i10 = y1c * WW + x0c;
        int i11 = y1c * WW + x1c;

        for (int c = 0; c < CC; ++c) {
            const float* xc = xb + c * (HH * WW);
            float g = w00 * xc[i00] + w01 * xc[i01] + w10 * xc[i10] + w11 * xc[i11];
            acc = fmaf(g, s_dw[c * KK + k], acc);
        }
    }

    out[pix] = acc;
}

extern "C" void kernel_launch(void* const* d_in, const int* in_sizes, int n_in,
                              void* d_out, int out_size, void* d_ws, size_t ws_size,
                              hipStream_t stream) {
    const float* x        = (const float*)d_in[0];
    const float* offset_w = (const float*)d_in[1];
    const float* offset_b = (const float*)d_in[2];
    const float* deform_w = (const float*)d_in[3];
    const float* deform_b = (const float*)d_in[4];
    float* out = (float*)d_out;

    const int npix = BB * HO * WO;
    dim3 block(256);
    dim3 grid((npix + 255) / 256);
    hipLaunchKernelGGL(deform_fused_kernel, grid, block, 0, stream,
                       x, offset_w, offset_b, deform_w, deform_b, out);
}